// Round 2
// baseline (102.977 us; speedup 1.0000x reference)
//
#include <hip/hip_runtime.h>
#include <hip/hip_bf16.h>

#define NN 4096      // N = 2*B
#define BB 2048      // B
#define DD 512       // D
#define TM 128       // C tile (M and N)
#define BK 64        // K tile
#define NTILE (NN/TM)                 // 32
#define NPAIR (NTILE*(NTILE+1)/2)     // 528 blocks: bi <= bj
#define NSLOT (NTILE*2)               // 64 partial slots per row

typedef __bf16 bf16x8 __attribute__((ext_vector_type(8)));
typedef float  f32x4  __attribute__((ext_vector_type(4)));

// async global->LDS, 16B per lane. LDS dest must be wave-uniform base + lane*16.
#define GLOAD_LDS16(gsrc, ldst)                                                  \
    __builtin_amdgcn_global_load_lds(                                            \
        (__attribute__((address_space(1))) void*)(gsrc),                         \
        (__attribute__((address_space(3))) void*)(ldst), 16, 0, 0)

__device__ __forceinline__ unsigned short f2bf(float x) {
    unsigned int u = __float_as_uint(x);
    unsigned int r = (u + 0x7fffu + ((u >> 16) & 1u)) >> 16;  // RNE; inputs finite
    return (unsigned short)r;
}

// ---------------------------------------------------------------------------
// Kernel A: row-normalize z = [z_i; z_j] -> bf16 zn[N][D]; zero-inits out[0]
// (stream order makes it visible to kernel C).
// ---------------------------------------------------------------------------
__global__ __launch_bounds__(256) void normalize_kernel(
        const float* __restrict__ z_i, const float* __restrict__ z_j,
        unsigned short* __restrict__ zn, float* __restrict__ out) {
    if (blockIdx.x == 0 && threadIdx.x == 0) out[0] = 0.f;

    int row  = blockIdx.x * 4 + (threadIdx.x >> 6);
    int lane = threadIdx.x & 63;
    const float* src = (row < BB) ? (z_i + (size_t)row * DD)
                                  : (z_j + (size_t)(row - BB) * DD);
    const float4* s4 = (const float4*)src;
    float4 v0 = s4[lane * 2 + 0];
    float4 v1 = s4[lane * 2 + 1];
    float ss = v0.x*v0.x + v0.y*v0.y + v0.z*v0.z + v0.w*v0.w
             + v1.x*v1.x + v1.y*v1.y + v1.z*v1.z + v1.w*v1.w;
    #pragma unroll
    for (int off = 1; off < 64; off <<= 1) ss += __shfl_xor(ss, off, 64);
    float inv = 1.0f / fmaxf(sqrtf(ss), 1e-8f);

    float f[8] = {v0.x, v0.y, v0.z, v0.w, v1.x, v1.y, v1.z, v1.w};
    unsigned int p[4];
    #pragma unroll
    for (int k = 0; k < 4; ++k) {
        unsigned int lo = f2bf(f[2*k] * inv);
        unsigned int hi = f2bf(f[2*k+1] * inv);
        p[k] = lo | (hi << 16);
    }
    uint4 outv = make_uint4(p[0], p[1], p[2], p[3]);
    *(uint4*)(zn + (size_t)row * DD + lane * 8) = outv;
}

// ---------------------------------------------------------------------------
// Kernel B: sim = (zn @ zn^T) * 2, upper-triangular tiles only (bi <= bj).
// exp-partials written ATOMIC-FREE: each (tile, wave-half) owns a unique slot
//   rowpart of tile (bi,bj), wave col-half wc -> part[bj*2+wc][row]
//   colpart of tile (bi,bj), wave row-half wr -> part[bi*2+wr][col]
// Every part[k][r], k=0..63, is written exactly once across the 528 blocks.
// Also extracts selfsim (diag tiles) and possim (bj==bi+16 tiles).
// 128x128 C-tile / 256 threads (2x2 waves of 64x64), MFMA 16x16x32 bf16.
// K-loop is a double-buffered 2-phase pipeline (T3-minimum): stage next tile,
// compute current, ONE barrier per K-step; load latency hides under MFMA.
// ---------------------------------------------------------------------------
__global__ __launch_bounds__(256) void simexp_kernel(
        const unsigned short* __restrict__ zn, float* __restrict__ part,
        float* __restrict__ selfsim, float* __restrict__ possim) {
    __shared__ __align__(16) unsigned short As[2][TM * BK];   // 2 x 16 KB
    __shared__ __align__(16) unsigned short Bs[2][TM * BK];   // 2 x 16 KB

    // triangular decode: p -> (bi <= bj)
    int p  = blockIdx.x;
    int bj = (int)((sqrtf(8.0f * (float)p + 1.0f) - 1.0f) * 0.5f);
    while ((bj + 1) * (bj + 2) / 2 <= p) ++bj;
    while (bj * (bj + 1) / 2 > p) --bj;
    int bi = p - bj * (bj + 1) / 2;
    const bool diag = (bi == bj);

    const int tid  = threadIdx.x;
    const int wave = tid >> 6, lane = tid & 63;
    const int wr = wave >> 1, wc = wave & 1;   // 2x2 wave grid, 64x64 each
    const int lrow = lane & 15, quad = lane >> 4;

    f32x4 acc[4][4];
    #pragma unroll
    for (int i = 0; i < 4; ++i)
        #pragma unroll
        for (int j = 0; j < 4; ++j) acc[i][j] = (f32x4){0.f, 0.f, 0.f, 0.f};

    // stage one BK-slab into buffer `buf` (source-side XOR swizzle, linear LDS)
    auto stage = [&](int buf, int kb) {
        #pragma unroll
        for (int it = 0; it < 4; ++it) {
            int t  = it * 256 + tid;       // chunk-slot 0..1023
            int r  = t >> 3;               // tile row 0..127
            int cc = t & 7;                // LDS chunk slot
            int sc = cc ^ (r & 7);         // global source chunk (swizzle)
            GLOAD_LDS16(zn + (size_t)(bi * TM + r) * DD + kb + sc * 8,
                        &As[buf][t * 8]);
            if (!diag)
                GLOAD_LDS16(zn + (size_t)(bj * TM + r) * DD + kb + sc * 8,
                            &Bs[buf][t * 8]);
        }
    };

    // consume buffer `buf`: 2 K=32 steps, 32 MFMA
    auto compute = [&](int buf) {
        const unsigned short* Ab = As[buf];
        const unsigned short* Bb = diag ? As[buf] : Bs[buf];
        #pragma unroll
        for (int s = 0; s < 2; ++s) {
            bf16x8 a[4], b[4];
            #pragma unroll
            for (int ti = 0; ti < 4; ++ti) {
                int m = wr * 64 + ti * 16 + lrow;
                int q = (s * 4 + quad) ^ (m & 7);
                a[ti] = *(const bf16x8*)&Ab[m * BK + q * 8];
            }
            #pragma unroll
            for (int tj = 0; tj < 4; ++tj) {
                int n = wc * 64 + tj * 16 + lrow;
                int q = (s * 4 + quad) ^ (n & 7);
                b[tj] = *(const bf16x8*)&Bb[n * BK + q * 8];
            }
            #pragma unroll
            for (int ti = 0; ti < 4; ++ti)
                #pragma unroll
                for (int tj = 0; tj < 4; ++tj)
                    acc[ti][tj] = __builtin_amdgcn_mfma_f32_16x16x32_bf16(
                        a[ti], b[tj], acc[ti][tj], 0, 0, 0);
        }
    };

    // 2-phase pipeline: one __syncthreads (vmcnt(0)+lgkmcnt(0)+s_barrier) per
    // K-step; the next slab's loads are in flight while this slab computes.
    stage(0, 0);
    __syncthreads();
    #pragma unroll
    for (int kb_i = 0; kb_i < (DD / BK) - 1; ++kb_i) {
        int cur = kb_i & 1;
        stage(cur ^ 1, (kb_i + 1) * BK);
        compute(cur);
        __syncthreads();
    }
    compute(((DD / BK) - 1) & 1);

    // Epilogue. C/D layout (verified, absmax 0.0):
    //   tile row = wr*64 + ti*16 + quad*4 + reg, tile col = wc*64 + tj*16 + lrow
    float rowpart[4][4];   // [ti][reg]
    float colpart[4];      // [tj]
    #pragma unroll
    for (int i = 0; i < 4; ++i) {
        colpart[i] = 0.f;
        #pragma unroll
        for (int r = 0; r < 4; ++r) rowpart[i][r] = 0.f;
    }
    #pragma unroll
    for (int ti = 0; ti < 4; ++ti)
        #pragma unroll
        for (int tj = 0; tj < 4; ++tj)
            #pragma unroll
            for (int reg = 0; reg < 4; ++reg) {
                float e = __expf(acc[ti][tj][reg] * 2.0f);
                rowpart[ti][reg] += e;
                colpart[tj]      += e;
            }

    // row-partials: reduce over lrow (16-lane groups); plain store, no atomics
    #pragma unroll
    for (int ti = 0; ti < 4; ++ti) {
        #pragma unroll
        for (int reg = 0; reg < 4; ++reg) {
            float v = rowpart[ti][reg];
            v += __shfl_xor(v, 1, 64);
            v += __shfl_xor(v, 2, 64);
            v += __shfl_xor(v, 4, 64);
            v += __shfl_xor(v, 8, 64);
            if (lrow == 0)
                part[(size_t)(bj * 2 + wc) * NN
                     + bi * TM + wr * 64 + ti * 16 + quad * 4 + reg] = v;
        }
    }
    // col-partials -> rows of bj tile (transpose); skip on diagonal tiles
    if (!diag) {
        #pragma unroll
        for (int tj = 0; tj < 4; ++tj) {
            float v = colpart[tj];
            v += __shfl_xor(v, 16, 64);
            v += __shfl_xor(v, 32, 64);
            if (quad == 0)
                part[(size_t)(bi * 2 + wr) * NN
                     + bj * TM + wc * 64 + tj * 16 + lrow] = v;
        }
    }

    // tile-diagonal extraction: lanes lrow>>2==quad in waves wr==wc hold
    // element (r, r) of the tile at acc[ti][ti][lrow&3], r = wr*64+ti*16+lrow.
    const bool posb = (bj == bi + NTILE / 2);   // bj == bi + 16  (col offset B)
    if ((diag || posb) && wr == wc && (lrow >> 2) == quad) {
        #pragma unroll
        for (int ti = 0; ti < 4; ++ti) {
            float v = 2.0f * acc[ti][ti][lrow & 3];
            int R = bi * TM + wr * 64 + ti * 16 + lrow;
            if (diag) {
                selfsim[R] = v;
            } else {
                possim[R]      = v;   // sim[r][r+B]
                possim[R + BB] = v;   // == sim[r+B][r]
            }
        }
    }
}

// ---------------------------------------------------------------------------
// Kernel C: rowsum_r = sum_k part[k][r] (64 coalesced L2-resident slabs);
// loss_r = log(rowsum_r - exp(selfsim_r)) - possim_r; block-reduce;
// atomicAdd(out, sum/N).
// ---------------------------------------------------------------------------
__global__ __launch_bounds__(256) void rowfinal_kernel(
        const float* __restrict__ part, const float* __restrict__ selfsim,
        const float* __restrict__ possim, float* __restrict__ out) {
    __shared__ float s[256];
    int r = blockIdx.x * 256 + threadIdx.x;
    float acc = 0.f;
    #pragma unroll
    for (int k = 0; k < NSLOT; ++k) acc += part[(size_t)k * NN + r];
    s[threadIdx.x] = logf(acc - __expf(selfsim[r])) - possim[r];
    __syncthreads();
    #pragma unroll
    for (int off = 128; off > 0; off >>= 1) {
        if (threadIdx.x < off) s[threadIdx.x] += s[threadIdx.x + off];
        __syncthreads();
    }
    if (threadIdx.x == 0) atomicAdd(out, s[0] * (1.0f / (float)NN));
}

extern "C" void kernel_launch(void* const* d_in, const int* in_sizes, int n_in,
                              void* d_out, int out_size, void* d_ws, size_t ws_size,
                              hipStream_t stream) {
    const float* z_i = (const float*)d_in[0];
    const float* z_j = (const float*)d_in[1];
    float* out = (float*)d_out;

    unsigned short* zn = (unsigned short*)d_ws;                    // N*D bf16 = 4 MB
    float* selfsim = (float*)((char*)d_ws + (size_t)NN * DD * 2);  // N floats
    float* possim  = selfsim + NN;                                 // N floats
    float* part    = possim + NN;                                  // 64*N floats = 1 MB

    normalize_kernel<<<NN / 4, 256, 0, stream>>>(z_i, z_j, zn, out);
    simexp_kernel<<<NPAIR, 256, 0, stream>>>(zn, part, selfsim, possim);
    rowfinal_kernel<<<NN / 256, 256, 0, stream>>>(part, selfsim, possim, out);
}

// Round 3
// 102.810 us; speedup vs baseline: 1.0016x; 1.0016x over previous
//
#include <hip/hip_runtime.h>
#include <hip/hip_bf16.h>

#define NN 4096      // N = 2*B
#define BB 2048      // B
#define DD 512       // D
#define TM 128       // C tile (M and N)
#define BK 64        // K tile
#define NTILE (NN/TM)                 // 32
#define NPAIR (NTILE*(NTILE+1)/2)     // 528 blocks: bi <= bj
#define NSLOT (NTILE*2)               // 64 partial slots per row

typedef __bf16 bf16x8 __attribute__((ext_vector_type(8)));
typedef float  f32x4  __attribute__((ext_vector_type(4)));

// async global->LDS, 16B per lane. LDS dest must be wave-uniform base + lane*16.
#define GLOAD_LDS16(gsrc, ldst)                                                  \
    __builtin_amdgcn_global_load_lds(                                            \
        (__attribute__((address_space(1))) void*)(gsrc),                         \
        (__attribute__((address_space(3))) void*)(ldst), 16, 0, 0)

__device__ __forceinline__ unsigned short f2bf(float x) {
    unsigned int u = __float_as_uint(x);
    unsigned int r = (u + 0x7fffu + ((u >> 16) & 1u)) >> 16;  // RNE; inputs finite
    return (unsigned short)r;
}

// ---------------------------------------------------------------------------
// Kernel A: row-normalize z = [z_i; z_j] -> bf16 zn[N][D]; zero-inits out[0]
// (stream order makes it visible to kernel C). No rowsum zeroing needed:
// the exp-partial buffer is written exactly-once by kernel B.
// ---------------------------------------------------------------------------
__global__ __launch_bounds__(256) void normalize_kernel(
        const float* __restrict__ z_i, const float* __restrict__ z_j,
        unsigned short* __restrict__ zn, float* __restrict__ out) {
    if (blockIdx.x == 0 && threadIdx.x == 0) out[0] = 0.f;

    int row  = blockIdx.x * 4 + (threadIdx.x >> 6);
    int lane = threadIdx.x & 63;
    const float* src = (row < BB) ? (z_i + (size_t)row * DD)
                                  : (z_j + (size_t)(row - BB) * DD);
    const float4* s4 = (const float4*)src;
    float4 v0 = s4[lane * 2 + 0];
    float4 v1 = s4[lane * 2 + 1];
    float ss = v0.x*v0.x + v0.y*v0.y + v0.z*v0.z + v0.w*v0.w
             + v1.x*v1.x + v1.y*v1.y + v1.z*v1.z + v1.w*v1.w;
    #pragma unroll
    for (int off = 1; off < 64; off <<= 1) ss += __shfl_xor(ss, off, 64);
    float inv = 1.0f / fmaxf(sqrtf(ss), 1e-8f);

    float f[8] = {v0.x, v0.y, v0.z, v0.w, v1.x, v1.y, v1.z, v1.w};
    unsigned int p[4];
    #pragma unroll
    for (int k = 0; k < 4; ++k) {
        unsigned int lo = f2bf(f[2*k] * inv);
        unsigned int hi = f2bf(f[2*k+1] * inv);
        p[k] = lo | (hi << 16);
    }
    uint4 outv = make_uint4(p[0], p[1], p[2], p[3]);
    *(uint4*)(zn + (size_t)row * DD + lane * 8) = outv;
}

// ---------------------------------------------------------------------------
// Kernel B: sim = (zn @ zn^T) * 2, upper-triangular tiles only (bi <= bj).
// HOT LOOP: exact baseline structure (single-buffer 32 KB LDS, two barriers
// per K-step) — the known-good 87 µs configuration.  (Round-1's 2-phase
// double-buffer regressed; reverted.)
// EPILOGUE: atomic-free. Each (tile, wave-half) owns a unique slot:
//   rowpart of tile (bi,bj), wave col-half wc -> part[bj*2+wc][row]
//   colpart of tile (bi,bj), wave row-half wr -> part[bi*2+wr][col]
// Every part[k][r], k=0..63, is written exactly once across the 528 blocks.
// Also extracts selfsim (diag tiles) and possim (bj==bi+16 tiles).
// ---------------------------------------------------------------------------
__global__ __launch_bounds__(256) void simexp_kernel(
        const unsigned short* __restrict__ zn, float* __restrict__ part,
        float* __restrict__ selfsim, float* __restrict__ possim) {
    __shared__ __align__(16) unsigned short As[TM * BK];
    __shared__ __align__(16) unsigned short Bs[TM * BK];

    // triangular decode: p -> (bi <= bj)
    int p  = blockIdx.x;
    int bj = (int)((sqrtf(8.0f * (float)p + 1.0f) - 1.0f) * 0.5f);
    while ((bj + 1) * (bj + 2) / 2 <= p) ++bj;
    while (bj * (bj + 1) / 2 > p) --bj;
    int bi = p - bj * (bj + 1) / 2;
    const bool diag = (bi == bj);

    const int tid  = threadIdx.x;
    const int wave = tid >> 6, lane = tid & 63;
    const int wr = wave >> 1, wc = wave & 1;   // 2x2 wave grid, 64x64 each
    const int lrow = lane & 15, quad = lane >> 4;

    f32x4 acc[4][4];
    #pragma unroll
    for (int i = 0; i < 4; ++i)
        #pragma unroll
        for (int j = 0; j < 4; ++j) acc[i][j] = (f32x4){0.f, 0.f, 0.f, 0.f};

    const unsigned short* Bsrc = diag ? As : Bs;   // diag tiles reuse As

    for (int kb = 0; kb < DD; kb += BK) {
        __syncthreads();   // protect LDS from previous iter's readers
        #pragma unroll
        for (int it = 0; it < 4; ++it) {
            int t  = it * 256 + tid;       // chunk-slot 0..1023
            int r  = t >> 3;               // tile row 0..127
            int cc = t & 7;                // LDS chunk slot
            int sc = cc ^ (r & 7);         // global source chunk (swizzle)
            GLOAD_LDS16(zn + (size_t)(bi * TM + r) * DD + kb + sc * 8, As + t * 8);
            if (!diag)
                GLOAD_LDS16(zn + (size_t)(bj * TM + r) * DD + kb + sc * 8, Bs + t * 8);
        }
        __syncthreads();   // drains vmcnt(0) before LDS reads

        #pragma unroll
        for (int s = 0; s < 2; ++s) {      // two K=32 steps per BK=64
            bf16x8 a[4], b[4];
            #pragma unroll
            for (int ti = 0; ti < 4; ++ti) {
                int m = wr * 64 + ti * 16 + lrow;
                int q = (s * 4 + quad) ^ (m & 7);
                a[ti] = *(const bf16x8*)&As[m * BK + q * 8];
            }
            #pragma unroll
            for (int tj = 0; tj < 4; ++tj) {
                int n = wc * 64 + tj * 16 + lrow;
                int q = (s * 4 + quad) ^ (n & 7);
                b[tj] = *(const bf16x8*)&Bsrc[n * BK + q * 8];
            }
            #pragma unroll
            for (int ti = 0; ti < 4; ++ti)
                #pragma unroll
                for (int tj = 0; tj < 4; ++tj)
                    acc[ti][tj] = __builtin_amdgcn_mfma_f32_16x16x32_bf16(
                        a[ti], b[tj], acc[ti][tj], 0, 0, 0);
        }
    }

    // Epilogue. C/D layout (verified, absmax 0.0):
    //   tile row = wr*64 + ti*16 + quad*4 + reg, tile col = wc*64 + tj*16 + lrow
    float rowpart[4][4];   // [ti][reg]
    float colpart[4];      // [tj]
    #pragma unroll
    for (int i = 0; i < 4; ++i) {
        colpart[i] = 0.f;
        #pragma unroll
        for (int r = 0; r < 4; ++r) rowpart[i][r] = 0.f;
    }
    #pragma unroll
    for (int ti = 0; ti < 4; ++ti)
        #pragma unroll
        for (int tj = 0; tj < 4; ++tj)
            #pragma unroll
            for (int reg = 0; reg < 4; ++reg) {
                float e = __expf(acc[ti][tj][reg] * 2.0f);
                rowpart[ti][reg] += e;
                colpart[tj]      += e;
            }

    // row-partials: reduce over lrow (16-lane groups); plain store, no atomics
    #pragma unroll
    for (int ti = 0; ti < 4; ++ti) {
        #pragma unroll
        for (int reg = 0; reg < 4; ++reg) {
            float v = rowpart[ti][reg];
            v += __shfl_xor(v, 1, 64);
            v += __shfl_xor(v, 2, 64);
            v += __shfl_xor(v, 4, 64);
            v += __shfl_xor(v, 8, 64);
            if (lrow == 0)
                part[(size_t)(bj * 2 + wc) * NN
                     + bi * TM + wr * 64 + ti * 16 + quad * 4 + reg] = v;
        }
    }
    // col-partials -> rows of bj tile (transpose); skip on diagonal tiles
    if (!diag) {
        #pragma unroll
        for (int tj = 0; tj < 4; ++tj) {
            float v = colpart[tj];
            v += __shfl_xor(v, 16, 64);
            v += __shfl_xor(v, 32, 64);
            if (quad == 0)
                part[(size_t)(bi * 2 + wr) * NN
                     + bj * TM + wc * 64 + tj * 16 + lrow] = v;
        }
    }

    // tile-diagonal extraction: lanes lrow>>2==quad in waves wr==wc hold
    // element (r, r) of the tile at acc[ti][ti][lrow&3], r = wr*64+ti*16+lrow.
    const bool posb = (bj == bi + NTILE / 2);   // bj == bi + 16  (col offset B)
    if ((diag || posb) && wr == wc && (lrow >> 2) == quad) {
        #pragma unroll
        for (int ti = 0; ti < 4; ++ti) {
            float v = 2.0f * acc[ti][ti][lrow & 3];
            int R = bi * TM + wr * 64 + ti * 16 + lrow;
            if (diag) {
                selfsim[R] = v;
            } else {
                possim[R]      = v;   // sim[r][r+B]
                possim[R + BB] = v;   // == sim[r+B][r]
            }
        }
    }
}

// ---------------------------------------------------------------------------
// Kernel C: rowsum_r = sum_k part[k][r] (64 coalesced L2-resident slabs);
// loss_r = log(rowsum_r - exp(selfsim_r)) - possim_r; block-reduce;
// atomicAdd(out, sum/N).
// ---------------------------------------------------------------------------
__global__ __launch_bounds__(256) void rowfinal_kernel(
        const float* __restrict__ part, const float* __restrict__ selfsim,
        const float* __restrict__ possim, float* __restrict__ out) {
    __shared__ float s[256];
    int r = blockIdx.x * 256 + threadIdx.x;
    float acc = 0.f;
    #pragma unroll
    for (int k = 0; k < NSLOT; ++k) acc += part[(size_t)k * NN + r];
    s[threadIdx.x] = logf(acc - __expf(selfsim[r])) - possim[r];
    __syncthreads();
    #pragma unroll
    for (int off = 128; off > 0; off >>= 1) {
        if (threadIdx.x < off) s[threadIdx.x] += s[threadIdx.x + off];
        __syncthreads();
    }
    if (threadIdx.x == 0) atomicAdd(out, s[0] * (1.0f / (float)NN));
}

extern "C" void kernel_launch(void* const* d_in, const int* in_sizes, int n_in,
                              void* d_out, int out_size, void* d_ws, size_t ws_size,
                              hipStream_t stream) {
    const float* z_i = (const float*)d_in[0];
    const float* z_j = (const float*)d_in[1];
    float* out = (float*)d_out;

    unsigned short* zn = (unsigned short*)d_ws;                    // N*D bf16 = 4 MB
    float* selfsim = (float*)((char*)d_ws + (size_t)NN * DD * 2);  // N floats
    float* possim  = selfsim + NN;                                 // N floats
    float* part    = possim + NN;                                  // 64*N floats = 1 MB

    normalize_kernel<<<NN / 4, 256, 0, stream>>>(z_i, z_j, zn, out);
    simexp_kernel<<<NPAIR, 256, 0, stream>>>(zn, part, selfsim, possim);
    rowfinal_kernel<<<NN / 256, 256, 0, stream>>>(part, selfsim, possim, out);
}

// Round 4
// 87.444 us; speedup vs baseline: 1.1776x; 1.1757x over previous
//
#include <hip/hip_runtime.h>
#include <hip/hip_bf16.h>

#define NN 4096      // N = 2*B
#define BB 2048      // B
#define DD 512       // D
#define TM 128       // C tile (M and N)
#define BK 64        // K tile
#define NTILE (NN/TM)                 // 32
#define NPAIR (NTILE*(NTILE+1)/2)     // 528 blocks: bi <= bj

typedef __bf16 bf16x8 __attribute__((ext_vector_type(8)));
typedef float  f32x4  __attribute__((ext_vector_type(4)));

// async global->LDS, 16B per lane. LDS dest must be wave-uniform base + lane*16.
#define GLOAD_LDS16(gsrc, ldst)                                                  \
    __builtin_amdgcn_global_load_lds(                                            \
        (__attribute__((address_space(1))) void*)(gsrc),                         \
        (__attribute__((address_space(3))) void*)(ldst), 16, 0, 0)

__device__ __forceinline__ unsigned short f2bf(float x) {
    unsigned int u = __float_as_uint(x);
    unsigned int r = (u + 0x7fffu + ((u >> 16) & 1u)) >> 16;  // RNE; inputs finite
    return (unsigned short)r;
}

// ---------------------------------------------------------------------------
// Kernel A: row-normalize z = [z_i; z_j] -> bf16 zn[N][D]; also zero-inits
// rowsum[] and out[0] (stream order makes these visible to later kernels),
// eliminating both hipMemsetAsync dispatches.
// ---------------------------------------------------------------------------
__global__ __launch_bounds__(256) void normalize_kernel(
        const float* __restrict__ z_i, const float* __restrict__ z_j,
        unsigned short* __restrict__ zn, float* __restrict__ rowsum,
        float* __restrict__ out) {
    if (threadIdx.x < 4) rowsum[blockIdx.x * 4 + threadIdx.x] = 0.f;
    if (blockIdx.x == 0 && threadIdx.x == 0) out[0] = 0.f;

    int row  = blockIdx.x * 4 + (threadIdx.x >> 6);
    int lane = threadIdx.x & 63;
    const float* src = (row < BB) ? (z_i + (size_t)row * DD)
                                  : (z_j + (size_t)(row - BB) * DD);
    const float4* s4 = (const float4*)src;
    float4 v0 = s4[lane * 2 + 0];
    float4 v1 = s4[lane * 2 + 1];
    float ss = v0.x*v0.x + v0.y*v0.y + v0.z*v0.z + v0.w*v0.w
             + v1.x*v1.x + v1.y*v1.y + v1.z*v1.z + v1.w*v1.w;
    #pragma unroll
    for (int off = 1; off < 64; off <<= 1) ss += __shfl_xor(ss, off, 64);
    float inv = 1.0f / fmaxf(sqrtf(ss), 1e-8f);

    float f[8] = {v0.x, v0.y, v0.z, v0.w, v1.x, v1.y, v1.z, v1.w};
    unsigned int p[4];
    #pragma unroll
    for (int k = 0; k < 4; ++k) {
        unsigned int lo = f2bf(f[2*k] * inv);
        unsigned int hi = f2bf(f[2*k+1] * inv);
        p[k] = lo | (hi << 16);
    }
    uint4 outv = make_uint4(p[0], p[1], p[2], p[3]);
    *(uint4*)(zn + (size_t)row * DD + lane * 8) = outv;
}

// ---------------------------------------------------------------------------
// Kernel B: sim = (zn @ zn^T) * 2, upper-triangular tiles only (bi <= bj).
// rowsum[r] += sum_j exp(sim[r][j]) via row-sums + (off-diag) col-sums.
// Additionally extracts the matrix entries the loss needs:
//   diag tiles (bi==bj):  selfsim[r] = sim[r][r]
//   pos tiles (bj==bi+16): possim[r] = possim[r+B] = sim[r][r+B]
// so the final kernel never re-reads zn.
// 128x128 C-tile / 256 threads (2x2 waves of 64x64), MFMA 16x16x32 bf16,
// global_load_lds width=16 staging with source-side XOR swizzle.
// ---------------------------------------------------------------------------
__global__ __launch_bounds__(256) void simexp_kernel(
        const unsigned short* __restrict__ zn, float* __restrict__ rowsum,
        float* __restrict__ selfsim, float* __restrict__ possim) {
    __shared__ __align__(16) unsigned short As[TM * BK];
    __shared__ __align__(16) unsigned short Bs[TM * BK];

    // triangular decode: p -> (bi <= bj)
    int p  = blockIdx.x;
    int bj = (int)((sqrtf(8.0f * (float)p + 1.0f) - 1.0f) * 0.5f);
    while ((bj + 1) * (bj + 2) / 2 <= p) ++bj;
    while (bj * (bj + 1) / 2 > p) --bj;
    int bi = p - bj * (bj + 1) / 2;
    const bool diag = (bi == bj);

    const int tid  = threadIdx.x;
    const int wave = tid >> 6, lane = tid & 63;
    const int wr = wave >> 1, wc = wave & 1;   // 2x2 wave grid, 64x64 each
    const int lrow = lane & 15, quad = lane >> 4;

    f32x4 acc[4][4];
    #pragma unroll
    for (int i = 0; i < 4; ++i)
        #pragma unroll
        for (int j = 0; j < 4; ++j) acc[i][j] = (f32x4){0.f, 0.f, 0.f, 0.f};

    const unsigned short* Bsrc = diag ? As : Bs;   // diag tiles reuse As

    for (int kb = 0; kb < DD; kb += BK) {
        __syncthreads();   // protect LDS from previous iter's readers
        #pragma unroll
        for (int it = 0; it < 4; ++it) {
            int t  = it * 256 + tid;       // chunk-slot 0..1023
            int r  = t >> 3;               // tile row 0..127
            int cc = t & 7;                // LDS chunk slot
            int sc = cc ^ (r & 7);         // global source chunk (swizzle)
            GLOAD_LDS16(zn + (size_t)(bi * TM + r) * DD + kb + sc * 8, As + t * 8);
            if (!diag)
                GLOAD_LDS16(zn + (size_t)(bj * TM + r) * DD + kb + sc * 8, Bs + t * 8);
        }
        __syncthreads();   // drains vmcnt(0) before LDS reads

        #pragma unroll
        for (int s = 0; s < 2; ++s) {      // two K=32 steps per BK=64
            bf16x8 a[4], b[4];
            #pragma unroll
            for (int ti = 0; ti < 4; ++ti) {
                int m = wr * 64 + ti * 16 + lrow;
                int q = (s * 4 + quad) ^ (m & 7);
                a[ti] = *(const bf16x8*)&As[m * BK + q * 8];
            }
            #pragma unroll
            for (int tj = 0; tj < 4; ++tj) {
                int n = wc * 64 + tj * 16 + lrow;
                int q = (s * 4 + quad) ^ (n & 7);
                b[tj] = *(const bf16x8*)&Bsrc[n * BK + q * 8];
            }
            #pragma unroll
            for (int ti = 0; ti < 4; ++ti)
                #pragma unroll
                for (int tj = 0; tj < 4; ++tj)
                    acc[ti][tj] = __builtin_amdgcn_mfma_f32_16x16x32_bf16(
                        a[ti], b[tj], acc[ti][tj], 0, 0, 0);
        }
    }

    // Epilogue. C/D layout (verified, absmax 0.0 in R0/R1):
    //   tile row = wr*64 + ti*16 + quad*4 + reg, tile col = wc*64 + tj*16 + lrow
    float rowpart[4][4];   // [ti][reg]
    float colpart[4];      // [tj]
    #pragma unroll
    for (int i = 0; i < 4; ++i) {
        colpart[i] = 0.f;
        #pragma unroll
        for (int r = 0; r < 4; ++r) rowpart[i][r] = 0.f;
    }
    #pragma unroll
    for (int ti = 0; ti < 4; ++ti)
        #pragma unroll
        for (int tj = 0; tj < 4; ++tj)
            #pragma unroll
            for (int reg = 0; reg < 4; ++reg) {
                float e = __expf(acc[ti][tj][reg] * 2.0f);
                rowpart[ti][reg] += e;
                colpart[tj]      += e;
            }

    // row-sums: reduce over lrow (16-lane groups)
    #pragma unroll
    for (int ti = 0; ti < 4; ++ti) {
        #pragma unroll
        for (int reg = 0; reg < 4; ++reg) {
            float v = rowpart[ti][reg];
            v += __shfl_xor(v, 1, 64);
            v += __shfl_xor(v, 2, 64);
            v += __shfl_xor(v, 4, 64);
            v += __shfl_xor(v, 8, 64);
            if (lrow == 0)
                atomicAdd(&rowsum[bi * TM + wr * 64 + ti * 16 + quad * 4 + reg], v);
        }
    }
    // col-sums -> rows of bj tile (transpose); skip on diagonal tiles
    if (!diag) {
        #pragma unroll
        for (int tj = 0; tj < 4; ++tj) {
            float v = colpart[tj];
            v += __shfl_xor(v, 16, 64);
            v += __shfl_xor(v, 32, 64);
            if (quad == 0)
                atomicAdd(&rowsum[bj * TM + wc * 64 + tj * 16 + lrow], v);
        }
    }

    // tile-diagonal extraction: lanes lrow>>2==quad in waves wr==wc hold
    // element (r, r) of the tile at acc[ti][ti][lrow&3], r = wr*64+ti*16+lrow.
    const bool posb = (bj == bi + NTILE / 2);   // bj == bi + 16  (col offset B)
    if ((diag || posb) && wr == wc && (lrow >> 2) == quad) {
        #pragma unroll
        for (int ti = 0; ti < 4; ++ti) {
            float v = 2.0f * acc[ti][ti][lrow & 3];
            int R = bi * TM + wr * 64 + ti * 16 + lrow;
            if (diag) {
                selfsim[R] = v;
            } else {
                possim[R]      = v;   // sim[r][r+B]
                possim[R + BB] = v;   // == sim[r+B][r]
            }
        }
    }
}

// ---------------------------------------------------------------------------
// Kernel C: loss_r = log(rowsum_r - exp(selfsim_r)) - possim_r; block-reduce;
// atomicAdd(out, sum/N). 3 float reads per row — no zn traffic.
// ---------------------------------------------------------------------------
__global__ __launch_bounds__(256) void rowfinal_kernel(
        const float* __restrict__ rowsum, const float* __restrict__ selfsim,
        const float* __restrict__ possim, float* __restrict__ out) {
    __shared__ float s[256];
    int r = blockIdx.x * 256 + threadIdx.x;
    s[threadIdx.x] = logf(rowsum[r] - __expf(selfsim[r])) - possim[r];
    __syncthreads();
    #pragma unroll
    for (int off = 128; off > 0; off >>= 1) {
        if (threadIdx.x < off) s[threadIdx.x] += s[threadIdx.x + off];
        __syncthreads();
    }
    if (threadIdx.x == 0) atomicAdd(out, s[0] * (1.0f / (float)NN));
}

extern "C" void kernel_launch(void* const* d_in, const int* in_sizes, int n_in,
                              void* d_out, int out_size, void* d_ws, size_t ws_size,
                              hipStream_t stream) {
    const float* z_i = (const float*)d_in[0];
    const float* z_j = (const float*)d_in[1];
    float* out = (float*)d_out;

    unsigned short* zn = (unsigned short*)d_ws;                    // N*D bf16 = 4 MB
    float* rowsum  = (float*)((char*)d_ws + (size_t)NN * DD * 2);  // N floats
    float* selfsim = rowsum + NN;                                  // N floats
    float* possim  = selfsim + NN;                                 // N floats

    normalize_kernel<<<NN / 4, 256, 0, stream>>>(z_i, z_j, zn, rowsum, out);
    simexp_kernel<<<NPAIR, 256, 0, stream>>>(zn, rowsum, selfsim, possim);
    rowfinal_kernel<<<NN / 256, 256, 0, stream>>>(rowsum, selfsim, possim, out);
}

// Round 5
// 85.308 us; speedup vs baseline: 1.2071x; 1.0250x over previous
//
#include <hip/hip_runtime.h>
#include <hip/hip_bf16.h>

#define NN 4096      // N = 2*B
#define BB 2048      // B
#define DD 512       // D
#define TM 128       // C tile (M and N)
#define BK 128       // K tile (R4: 64 -> 128; halves barrier drains, 4 K-iters)
#define NTILE (NN/TM)                 // 32
#define NPAIR (NTILE*(NTILE+1)/2)     // 528 blocks: bi <= bj

typedef __bf16 bf16x8 __attribute__((ext_vector_type(8)));
typedef float  f32x4  __attribute__((ext_vector_type(4)));

// async global->LDS, 16B per lane. LDS dest must be wave-uniform base + lane*16.
#define GLOAD_LDS16(gsrc, ldst)                                                  \
    __builtin_amdgcn_global_load_lds(                                            \
        (__attribute__((address_space(1))) void*)(gsrc),                         \
        (__attribute__((address_space(3))) void*)(ldst), 16, 0, 0)

__device__ __forceinline__ unsigned short f2bf(float x) {
    unsigned int u = __float_as_uint(x);
    unsigned int r = (u + 0x7fffu + ((u >> 16) & 1u)) >> 16;  // RNE; inputs finite
    return (unsigned short)r;
}

// ---------------------------------------------------------------------------
// Kernel A: row-normalize z = [z_i; z_j] -> bf16 zn[N][D]; also zero-inits
// rowsum[] and out[0] (stream order makes these visible to later kernels),
// eliminating both hipMemsetAsync dispatches.
// ---------------------------------------------------------------------------
__global__ __launch_bounds__(256) void normalize_kernel(
        const float* __restrict__ z_i, const float* __restrict__ z_j,
        unsigned short* __restrict__ zn, float* __restrict__ rowsum,
        float* __restrict__ out) {
    if (threadIdx.x < 4) rowsum[blockIdx.x * 4 + threadIdx.x] = 0.f;
    if (blockIdx.x == 0 && threadIdx.x == 0) out[0] = 0.f;

    int row  = blockIdx.x * 4 + (threadIdx.x >> 6);
    int lane = threadIdx.x & 63;
    const float* src = (row < BB) ? (z_i + (size_t)row * DD)
                                  : (z_j + (size_t)(row - BB) * DD);
    const float4* s4 = (const float4*)src;
    float4 v0 = s4[lane * 2 + 0];
    float4 v1 = s4[lane * 2 + 1];
    float ss = v0.x*v0.x + v0.y*v0.y + v0.z*v0.z + v0.w*v0.w
             + v1.x*v1.x + v1.y*v1.y + v1.z*v1.z + v1.w*v1.w;
    #pragma unroll
    for (int off = 1; off < 64; off <<= 1) ss += __shfl_xor(ss, off, 64);
    float inv = 1.0f / fmaxf(sqrtf(ss), 1e-8f);

    float f[8] = {v0.x, v0.y, v0.z, v0.w, v1.x, v1.y, v1.z, v1.w};
    unsigned int p[4];
    #pragma unroll
    for (int k = 0; k < 4; ++k) {
        unsigned int lo = f2bf(f[2*k] * inv);
        unsigned int hi = f2bf(f[2*k+1] * inv);
        p[k] = lo | (hi << 16);
    }
    uint4 outv = make_uint4(p[0], p[1], p[2], p[3]);
    *(uint4*)(zn + (size_t)row * DD + lane * 8) = outv;
}

// ---------------------------------------------------------------------------
// Kernel B: sim = (zn @ zn^T) * 2, upper-triangular tiles only (bi <= bj).
// rowsum[r] += sum_j exp(sim[r][j]) via row-sums + (off-diag) col-sums
// (atomics: measured faster than the exactly-once part[] scheme by ~15 us,
// rounds 1-4 A/B).  Extracts selfsim (diag tiles) / possim (bj==bi+16).
// 128x128 C-tile / 256 threads (2x2 waves of 64x64), MFMA 16x16x32 bf16,
// global_load_lds width=16 staging with source-side XOR swizzle.
// R4: BK=128 -> 4 K-iterations, 4 barrier-drains/block instead of 8,
// 64 MFMA + 16 staging loads per thread between drains (grid-capped
// occupancy 2.06 blocks/CU is unchanged by the 64 KB LDS).
// Row = 128 cols = 16 chunks of 16 B; swizzle chunk ^= (row & 15):
// 16 lanes of a quad-group hit 16 distinct chunks -> worst 2-way bank
// aliasing (free, m136).
// ---------------------------------------------------------------------------
__global__ __launch_bounds__(256) void simexp_kernel(
        const unsigned short* __restrict__ zn, float* __restrict__ rowsum,
        float* __restrict__ selfsim, float* __restrict__ possim) {
    __shared__ __align__(16) unsigned short As[TM * BK];   // 32 KB
    __shared__ __align__(16) unsigned short Bs[TM * BK];   // 32 KB

    // triangular decode: p -> (bi <= bj)
    int p  = blockIdx.x;
    int bj = (int)((sqrtf(8.0f * (float)p + 1.0f) - 1.0f) * 0.5f);
    while ((bj + 1) * (bj + 2) / 2 <= p) ++bj;
    while (bj * (bj + 1) / 2 > p) --bj;
    int bi = p - bj * (bj + 1) / 2;
    const bool diag = (bi == bj);

    const int tid  = threadIdx.x;
    const int wave = tid >> 6, lane = tid & 63;
    const int wr = wave >> 1, wc = wave & 1;   // 2x2 wave grid, 64x64 each
    const int lrow = lane & 15, quad = lane >> 4;

    f32x4 acc[4][4];
    #pragma unroll
    for (int i = 0; i < 4; ++i)
        #pragma unroll
        for (int j = 0; j < 4; ++j) acc[i][j] = (f32x4){0.f, 0.f, 0.f, 0.f};

    const unsigned short* Bsrc = diag ? As : Bs;   // diag tiles reuse As

    for (int kb = 0; kb < DD; kb += BK) {
        __syncthreads();   // protect LDS from previous iter's readers
        #pragma unroll
        for (int it = 0; it < 8; ++it) {
            int t  = it * 256 + tid;       // chunk-slot 0..2047
            int r  = t >> 4;               // tile row 0..127
            int cc = t & 15;               // LDS chunk slot (16 per row)
            int sc = cc ^ (r & 15);        // global source chunk (swizzle)
            GLOAD_LDS16(zn + (size_t)(bi * TM + r) * DD + kb + sc * 8, As + t * 8);
            if (!diag)
                GLOAD_LDS16(zn + (size_t)(bj * TM + r) * DD + kb + sc * 8, Bs + t * 8);
        }
        __syncthreads();   // drains vmcnt(0) before LDS reads

        #pragma unroll
        for (int s = 0; s < 4; ++s) {      // four K=32 steps per BK=128
            bf16x8 a[4], b[4];
            #pragma unroll
            for (int ti = 0; ti < 4; ++ti) {
                int m = wr * 64 + ti * 16 + lrow;
                int q = (s * 4 + quad) ^ (m & 15);
                a[ti] = *(const bf16x8*)&As[m * BK + q * 8];
            }
            #pragma unroll
            for (int tj = 0; tj < 4; ++tj) {
                int n = wc * 64 + tj * 16 + lrow;
                int q = (s * 4 + quad) ^ (n & 15);
                b[tj] = *(const bf16x8*)&Bsrc[n * BK + q * 8];
            }
            #pragma unroll
            for (int ti = 0; ti < 4; ++ti)
                #pragma unroll
                for (int tj = 0; tj < 4; ++tj)
                    acc[ti][tj] = __builtin_amdgcn_mfma_f32_16x16x32_bf16(
                        a[ti], b[tj], acc[ti][tj], 0, 0, 0);
        }
    }

    // Epilogue. C/D layout (verified, absmax 0.0 in R0/R1):
    //   tile row = wr*64 + ti*16 + quad*4 + reg, tile col = wc*64 + tj*16 + lrow
    float rowpart[4][4];   // [ti][reg]
    float colpart[4];      // [tj]
    #pragma unroll
    for (int i = 0; i < 4; ++i) {
        colpart[i] = 0.f;
        #pragma unroll
        for (int r = 0; r < 4; ++r) rowpart[i][r] = 0.f;
    }
    #pragma unroll
    for (int ti = 0; ti < 4; ++ti)
        #pragma unroll
        for (int tj = 0; tj < 4; ++tj)
            #pragma unroll
            for (int reg = 0; reg < 4; ++reg) {
                float e = __expf(acc[ti][tj][reg] * 2.0f);
                rowpart[ti][reg] += e;
                colpart[tj]      += e;
            }

    // row-sums: reduce over lrow (16-lane groups)
    #pragma unroll
    for (int ti = 0; ti < 4; ++ti) {
        #pragma unroll
        for (int reg = 0; reg < 4; ++reg) {
            float v = rowpart[ti][reg];
            v += __shfl_xor(v, 1, 64);
            v += __shfl_xor(v, 2, 64);
            v += __shfl_xor(v, 4, 64);
            v += __shfl_xor(v, 8, 64);
            if (lrow == 0)
                atomicAdd(&rowsum[bi * TM + wr * 64 + ti * 16 + quad * 4 + reg], v);
        }
    }
    // col-sums -> rows of bj tile (transpose); skip on diagonal tiles
    if (!diag) {
        #pragma unroll
        for (int tj = 0; tj < 4; ++tj) {
            float v = colpart[tj];
            v += __shfl_xor(v, 16, 64);
            v += __shfl_xor(v, 32, 64);
            if (quad == 0)
                atomicAdd(&rowsum[bj * TM + wc * 64 + tj * 16 + lrow], v);
        }
    }

    // tile-diagonal extraction: lanes lrow>>2==quad in waves wr==wc hold
    // element (r, r) of the tile at acc[ti][ti][lrow&3], r = wr*64+ti*16+lrow.
    const bool posb = (bj == bi + NTILE / 2);   // bj == bi + 16  (col offset B)
    if ((diag || posb) && wr == wc && (lrow >> 2) == quad) {
        #pragma unroll
        for (int ti = 0; ti < 4; ++ti) {
            float v = 2.0f * acc[ti][ti][lrow & 3];
            int R = bi * TM + wr * 64 + ti * 16 + lrow;
            if (diag) {
                selfsim[R] = v;
            } else {
                possim[R]      = v;   // sim[r][r+B]
                possim[R + BB] = v;   // == sim[r+B][r]
            }
        }
    }
}

// ---------------------------------------------------------------------------
// Kernel C: loss_r = log(rowsum_r - exp(selfsim_r)) - possim_r; block-reduce;
// atomicAdd(out, sum/N). 3 float reads per row — no zn traffic.
// ---------------------------------------------------------------------------
__global__ __launch_bounds__(256) void rowfinal_kernel(
        const float* __restrict__ rowsum, const float* __restrict__ selfsim,
        const float* __restrict__ possim, float* __restrict__ out) {
    __shared__ float s[256];
    int r = blockIdx.x * 256 + threadIdx.x;
    s[threadIdx.x] = logf(rowsum[r] - __expf(selfsim[r])) - possim[r];
    __syncthreads();
    #pragma unroll
    for (int off = 128; off > 0; off >>= 1) {
        if (threadIdx.x < off) s[threadIdx.x] += s[threadIdx.x + off];
        __syncthreads();
    }
    if (threadIdx.x == 0) atomicAdd(out, s[0] * (1.0f / (float)NN));
}

extern "C" void kernel_launch(void* const* d_in, const int* in_sizes, int n_in,
                              void* d_out, int out_size, void* d_ws, size_t ws_size,
                              hipStream_t stream) {
    const float* z_i = (const float*)d_in[0];
    const float* z_j = (const float*)d_in[1];
    float* out = (float*)d_out;

    unsigned short* zn = (unsigned short*)d_ws;                    // N*D bf16 = 4 MB
    float* rowsum  = (float*)((char*)d_ws + (size_t)NN * DD * 2);  // N floats
    float* selfsim = rowsum + NN;                                  // N floats
    float* possim  = selfsim + NN;                                 // N floats

    normalize_kernel<<<NN / 4, 256, 0, stream>>>(z_i, z_j, zn, rowsum, out);
    simexp_kernel<<<NPAIR, 256, 0, stream>>>(zn, rowsum, selfsim, possim);
    rowfinal_kernel<<<NN / 256, 256, 0, stream>>>(rowsum, selfsim, possim, out);
}